// Round 1
// baseline (926.309 us; speedup 1.0000x reference)
//
#include <hip/hip_runtime.h>
#include <math.h>

// ClusterInversionLoss:
//   s[n]   = sum_k k * softmax(inputs[n])_k          (N=4e6, C=5)
//   per pair p: i=pair_i[p], j=pair_j[p]
//     sign = sgn(y_i - y_j); active = sign != 0
//     delta = sign*(s_i - s_j); loss = softplus(-delta)
//     contrib = loss * |y_i-y_j| * 0.5*(w_i+w_j) * active
//   out = sum(contrib) / (sum(0.5*(w_i+w_j)*active) + 1e-8)

#define NCLS 5

// Device-global accumulators (doubles). Zeroed by init_acc every call, so we
// never depend on d_ws/d_out poison state or prior-call state.
__device__ double g_loss_acc;
__device__ double g_w_acc;

__global__ void init_acc() {
    g_loss_acc = 0.0;
    g_w_acc = 0.0;
}

// Pass 1: build packed per-sample table: {s, w, y_as_float, 0} (16B).
// One 16B gather per pair-index in pass 2 instead of 3 scattered 4B gathers.
__global__ __launch_bounds__(256) void build_table(
        const float* __restrict__ inputs,
        const int*   __restrict__ targets,
        const float* __restrict__ weights,
        float4*      __restrict__ tab,
        int n) {
    int i = blockIdx.x * blockDim.x + threadIdx.x;
    if (i >= n) return;
    const float* p = inputs + (long long)i * NCLS;
    float x0 = p[0], x1 = p[1], x2 = p[2], x3 = p[3], x4 = p[4];
    float m = fmaxf(fmaxf(fmaxf(x0, x1), fmaxf(x2, x3)), x4);
    float e0 = __expf(x0 - m), e1 = __expf(x1 - m), e2 = __expf(x2 - m),
          e3 = __expf(x3 - m), e4 = __expf(x4 - m);
    float denom = e0 + e1 + e2 + e3 + e4;
    float num = e1 + 2.f * e2 + 3.f * e3 + 4.f * e4;
    float4 v;
    v.x = num / denom;                  // expected ordinal score s
    v.y = weights[i];                   // sample weight
    v.z = __int_as_float(targets[i]);   // class label (bit-stashed)
    v.w = 0.f;
    tab[i] = v;
}

__device__ __forceinline__ void wave_reduce_and_atomic(float lsum, float wsum,
                                                       int lane) {
    #pragma unroll
    for (int off = 32; off > 0; off >>= 1) {
        lsum += __shfl_down(lsum, off, 64);
        wsum += __shfl_down(wsum, off, 64);
    }
    if (lane == 0) {
        atomicAdd(&g_loss_acc, (double)lsum);
        atomicAdd(&g_w_acc, (double)wsum);
    }
}

// Pass 2 (fast path): gather packed entries, compute pair loss, reduce.
__global__ __launch_bounds__(256) void pair_kernel(
        const int*    __restrict__ pi,
        const int*    __restrict__ pj,
        const float4* __restrict__ tab,
        int npairs) {
    int idx = blockIdx.x * blockDim.x + threadIdx.x;
    float lsum = 0.f, wsum = 0.f;
    if (idx < npairs) {
        int i = pi[idx];
        int j = pj[idx];
        float4 a = tab[i];
        float4 b = tab[j];
        int yi = __float_as_int(a.z);
        int yj = __float_as_int(b.z);
        if (yi != yj) {                       // inactive pairs (incl. i==j) drop out
            float sgn   = (yi > yj) ? 1.f : -1.f;
            float delta = sgn * (a.x - b.x);
            float x     = -delta;             // MARGIN = 0
            // stable softplus: max(x,0) + log1p(exp(-|x|))
            float sp    = fmaxf(x, 0.f) + log1pf(__expf(-fabsf(x)));
            float dist  = fabsf((float)(yi - yj));
            float wp    = 0.5f * (a.y + b.y);
            lsum = sp * dist * wp;
            wsum = wp;
        }
    }
    wave_reduce_and_atomic(lsum, wsum, threadIdx.x & 63);
}

// Fallback (ws too small for the 16B table): gather raw rows + recompute
// softmax inline per pair endpoint.
__device__ __forceinline__ float score_of(const float* __restrict__ inputs, int i) {
    const float* p = inputs + (long long)i * NCLS;
    float x0 = p[0], x1 = p[1], x2 = p[2], x3 = p[3], x4 = p[4];
    float m = fmaxf(fmaxf(fmaxf(x0, x1), fmaxf(x2, x3)), x4);
    float e0 = __expf(x0 - m), e1 = __expf(x1 - m), e2 = __expf(x2 - m),
          e3 = __expf(x3 - m), e4 = __expf(x4 - m);
    return (e1 + 2.f * e2 + 3.f * e3 + 4.f * e4) / (e0 + e1 + e2 + e3 + e4);
}

__global__ __launch_bounds__(256) void pair_kernel_direct(
        const int*   __restrict__ pi,
        const int*   __restrict__ pj,
        const float* __restrict__ inputs,
        const int*   __restrict__ targets,
        const float* __restrict__ weights,
        int npairs) {
    int idx = blockIdx.x * blockDim.x + threadIdx.x;
    float lsum = 0.f, wsum = 0.f;
    if (idx < npairs) {
        int i = pi[idx];
        int j = pj[idx];
        int yi = targets[i];
        int yj = targets[j];
        if (yi != yj) {
            float si = score_of(inputs, i);
            float sj = score_of(inputs, j);
            float sgn   = (yi > yj) ? 1.f : -1.f;
            float x     = -(sgn * (si - sj));
            float sp    = fmaxf(x, 0.f) + log1pf(__expf(-fabsf(x)));
            float dist  = fabsf((float)(yi - yj));
            float wp    = 0.5f * (weights[i] + weights[j]);
            lsum = sp * dist * wp;
            wsum = wp;
        }
    }
    wave_reduce_and_atomic(lsum, wsum, threadIdx.x & 63);
}

__global__ void finalize(float* __restrict__ out) {
    out[0] = (float)(g_loss_acc / (g_w_acc + 1e-8));
}

extern "C" void kernel_launch(void* const* d_in, const int* in_sizes, int n_in,
                              void* d_out, int out_size, void* d_ws, size_t ws_size,
                              hipStream_t stream) {
    const float* inputs  = (const float*)d_in[0];   // (N, 5) f32
    const int*   targets = (const int*)d_in[1];     // (N,)  i32
    /* d_in[2] = cluster_ids — unused (pair sampling pre-materialized) */
    const float* weights = (const float*)d_in[3];   // (N,)  f32
    const int*   pair_i  = (const int*)d_in[4];     // (K*P,) i32
    const int*   pair_j  = (const int*)d_in[5];     // (K*P,) i32
    float*       out     = (float*)d_out;

    const int n      = in_sizes[1];   // N samples
    const int npairs = in_sizes[4];   // K*P pairs

    init_acc<<<1, 1, 0, stream>>>();

    const size_t tab_bytes = (size_t)n * sizeof(float4);
    if (ws_size >= tab_bytes) {
        float4* tab = (float4*)d_ws;
        build_table<<<(n + 255) / 256, 256, 0, stream>>>(inputs, targets, weights,
                                                         tab, n);
        pair_kernel<<<(npairs + 255) / 256, 256, 0, stream>>>(pair_i, pair_j, tab,
                                                              npairs);
    } else {
        pair_kernel_direct<<<(npairs + 255) / 256, 256, 0, stream>>>(
            pair_i, pair_j, inputs, targets, weights, npairs);
    }

    finalize<<<1, 1, 0, stream>>>(out);
}

// Round 2
// 233.628 us; speedup vs baseline: 3.9649x; 3.9649x over previous
//
#include <hip/hip_runtime.h>
#include <math.h>

// ClusterInversionLoss:
//   s[n]   = sum_k k * softmax(inputs[n])_k          (N=4e6, C=5)
//   per pair p: i=pair_i[p], j=pair_j[p]
//     sign = sgn(y_i - y_j); active = sign != 0
//     delta = sign*(s_i - s_j); loss = softplus(-delta)
//     contrib = loss * |y_i-y_j| * 0.5*(w_i+w_j) * active
//   out = sum(contrib) / (sum(0.5*(w_i+w_j)*active) + 1e-8)
//
// R1 lesson: per-wave device atomics to one cache line serialized the whole
// pair pass (768 us @ 275 GB/s, VALUBusy 1.4%). This round: block-level
// reduction (2 atomics/block), 4 pairs/thread with int4 index loads for MLP,
// and an 8-byte packed table entry {s, w|y} (y in w's 3 low mantissa bits).

#define NCLS 5

__device__ double g_loss_acc;
__device__ double g_w_acc;

__global__ void init_acc() {
    g_loss_acc = 0.0;
    g_w_acc = 0.0;
}

// Pass 1: packed per-sample table, 8 B: {s, weight with target in low 3 bits}.
__global__ __launch_bounds__(256) void build_table(
        const float* __restrict__ inputs,
        const int*   __restrict__ targets,
        const float* __restrict__ weights,
        float2*      __restrict__ tab,
        int n) {
    int i = blockIdx.x * blockDim.x + threadIdx.x;
    if (i >= n) return;
    const float* p = inputs + (long long)i * NCLS;
    float x0 = p[0], x1 = p[1], x2 = p[2], x3 = p[3], x4 = p[4];
    float m = fmaxf(fmaxf(fmaxf(x0, x1), fmaxf(x2, x3)), x4);
    float e0 = __expf(x0 - m), e1 = __expf(x1 - m), e2 = __expf(x2 - m),
          e3 = __expf(x3 - m), e4 = __expf(x4 - m);
    float s = (e1 + 2.f * e2 + 3.f * e3 + 4.f * e4) /
              (e0 + e1 + e2 + e3 + e4);
    unsigned wb = __float_as_uint(weights[i]);
    wb = (wb & ~7u) | ((unsigned)targets[i] & 7u);  // steal 3 ulps of w for y
    float2 v;
    v.x = s;
    v.y = __uint_as_float(wb);
    tab[i] = v;
}

__device__ __forceinline__ void pair_op(float2 a, float2 b,
                                        float& lsum, float& wsum) {
    unsigned ab = __float_as_uint(a.y), bb = __float_as_uint(b.y);
    int yi = (int)(ab & 7u), yj = (int)(bb & 7u);
    if (yi != yj) {
        float wi = __uint_as_float(ab & ~7u);
        float wj = __uint_as_float(bb & ~7u);
        float sgn  = (yi > yj) ? 1.f : -1.f;
        float x    = -(sgn * (a.x - b.x));                  // MARGIN = 0
        float sp   = fmaxf(x, 0.f) + log1pf(__expf(-fabsf(x)));
        float dist = fabsf((float)(yi - yj));
        float wp   = 0.5f * (wi + wj);
        lsum += sp * dist * wp;
        wsum += wp;
    }
}

__device__ __forceinline__ void block_reduce_atomic(float lsum, float wsum) {
    #pragma unroll
    for (int off = 32; off > 0; off >>= 1) {
        lsum += __shfl_down(lsum, off, 64);
        wsum += __shfl_down(wsum, off, 64);
    }
    __shared__ float2 red[4];
    int lane = threadIdx.x & 63, wid = threadIdx.x >> 6;
    if (lane == 0) red[wid] = make_float2(lsum, wsum);
    __syncthreads();
    if (threadIdx.x == 0) {
        float L = red[0].x + red[1].x + red[2].x + red[3].x;
        float W = red[0].y + red[1].y + red[2].y + red[3].y;
        atomicAdd(&g_loss_acc, (double)L);
        atomicAdd(&g_w_acc, (double)W);
    }
}

// Pass 2: 4 pairs per thread (int4 index loads -> 8 independent gathers in
// flight), block-level reduction, 2 atomics per block.
__global__ __launch_bounds__(256) void pair_kernel(
        const int*    __restrict__ pi,
        const int*    __restrict__ pj,
        const float2* __restrict__ tab,
        int npairs) {
    int t    = blockIdx.x * blockDim.x + threadIdx.x;
    int base = t * 4;
    float lsum = 0.f, wsum = 0.f;
    if (base + 3 < npairs) {
        int4 iv = ((const int4*)pi)[t];
        int4 jv = ((const int4*)pj)[t];
        float2 a0 = tab[iv.x], b0 = tab[jv.x];
        float2 a1 = tab[iv.y], b1 = tab[jv.y];
        float2 a2 = tab[iv.z], b2 = tab[jv.z];
        float2 a3 = tab[iv.w], b3 = tab[jv.w];
        pair_op(a0, b0, lsum, wsum);
        pair_op(a1, b1, lsum, wsum);
        pair_op(a2, b2, lsum, wsum);
        pair_op(a3, b3, lsum, wsum);
    } else if (base < npairs) {
        for (int k = base; k < npairs; ++k)
            pair_op(tab[pi[k]], tab[pj[k]], lsum, wsum);
    }
    block_reduce_atomic(lsum, wsum);
}

// Fallback if ws can't hold the 8B table: gather raw rows, recompute inline.
__device__ __forceinline__ float score_of(const float* __restrict__ inputs, int i) {
    const float* p = inputs + (long long)i * NCLS;
    float x0 = p[0], x1 = p[1], x2 = p[2], x3 = p[3], x4 = p[4];
    float m = fmaxf(fmaxf(fmaxf(x0, x1), fmaxf(x2, x3)), x4);
    float e0 = __expf(x0 - m), e1 = __expf(x1 - m), e2 = __expf(x2 - m),
          e3 = __expf(x3 - m), e4 = __expf(x4 - m);
    return (e1 + 2.f * e2 + 3.f * e3 + 4.f * e4) / (e0 + e1 + e2 + e3 + e4);
}

__global__ __launch_bounds__(256) void pair_kernel_direct(
        const int*   __restrict__ pi,
        const int*   __restrict__ pj,
        const float* __restrict__ inputs,
        const int*   __restrict__ targets,
        const float* __restrict__ weights,
        int npairs) {
    int t    = blockIdx.x * blockDim.x + threadIdx.x;
    int base = t * 4;
    float lsum = 0.f, wsum = 0.f;
    for (int k = base; k < min(base + 4, npairs); ++k) {
        int i = pi[k], j = pj[k];
        int yi = targets[i], yj = targets[j];
        if (yi != yj) {
            float si = score_of(inputs, i);
            float sj = score_of(inputs, j);
            float sgn  = (yi > yj) ? 1.f : -1.f;
            float x    = -(sgn * (si - sj));
            float sp   = fmaxf(x, 0.f) + log1pf(__expf(-fabsf(x)));
            float dist = fabsf((float)(yi - yj));
            float wp   = 0.5f * (weights[i] + weights[j]);
            lsum += sp * dist * wp;
            wsum += wp;
        }
    }
    block_reduce_atomic(lsum, wsum);
}

__global__ void finalize(float* __restrict__ out) {
    out[0] = (float)(g_loss_acc / (g_w_acc + 1e-8));
}

extern "C" void kernel_launch(void* const* d_in, const int* in_sizes, int n_in,
                              void* d_out, int out_size, void* d_ws, size_t ws_size,
                              hipStream_t stream) {
    const float* inputs  = (const float*)d_in[0];   // (N, 5) f32
    const int*   targets = (const int*)d_in[1];     // (N,)  i32
    /* d_in[2] = cluster_ids — unused (pair sampling pre-materialized) */
    const float* weights = (const float*)d_in[3];   // (N,)  f32
    const int*   pair_i  = (const int*)d_in[4];     // (K*P,) i32
    const int*   pair_j  = (const int*)d_in[5];     // (K*P,) i32
    float*       out     = (float*)d_out;

    const int n      = in_sizes[1];   // N samples
    const int npairs = in_sizes[4];   // K*P pairs

    init_acc<<<1, 1, 0, stream>>>();

    const size_t tab_bytes = (size_t)n * sizeof(float2);
    const int nthreads = (npairs + 3) / 4;            // 4 pairs per thread
    const int nblocks  = (nthreads + 255) / 256;

    if (ws_size >= tab_bytes) {
        float2* tab = (float2*)d_ws;
        build_table<<<(n + 255) / 256, 256, 0, stream>>>(inputs, targets,
                                                         weights, tab, n);
        pair_kernel<<<nblocks, 256, 0, stream>>>(pair_i, pair_j, tab, npairs);
    } else {
        pair_kernel_direct<<<nblocks, 256, 0, stream>>>(
            pair_i, pair_j, inputs, targets, weights, npairs);
    }

    finalize<<<1, 1, 0, stream>>>(out);
}